// Round 3
// baseline (240.556 us; speedup 1.0000x reference)
//
#include <hip/hip_runtime.h>

typedef unsigned short u16;
typedef unsigned int   u32;
typedef __attribute__((ext_vector_type(8))) short short8;
typedef __attribute__((ext_vector_type(4))) unsigned int u32x4;
typedef __attribute__((ext_vector_type(4))) float f32x4;

__device__ __forceinline__ u16 f2b(float f) {
    u32 u = __float_as_uint(f);
    u32 r = (u + 0x7fffu + ((u >> 16) & 1u)) >> 16;   // round-to-nearest-even
    return (u16)r;
}
__device__ __forceinline__ float b2f(u16 u) { return __uint_as_float(((u32)u) << 16); }
__device__ __forceinline__ float blo(u32 w) { return __uint_as_float(w << 16); }
__device__ __forceinline__ float bhi(u32 w) { return __uint_as_float(w & 0xffff0000u); }

// ---------------- prep weights (transpose+bf16) AND edge histogram, one launch ----------------
// blocks [0,320): Wt[g][j][k] = W_g[k][j];  blocks [320,...): histogram of dst
__global__ void k_ph(const float* __restrict__ W0, const float* __restrict__ W1,
                     const float* __restrict__ W2, const float* __restrict__ W3,
                     const float* __restrict__ W4, u16* __restrict__ Wt,
                     const int* __restrict__ dst, int* __restrict__ cnt, int E) {
    int b = blockIdx.x, t = threadIdx.x;
    if (b < 320) {
        int id = b * 256 + t;
        if (id < 5 * 16384) {
            int g = id >> 14, j = (id >> 7) & 127, k = id & 127;
            const float* W = g == 0 ? W0 : g == 1 ? W1 : g == 2 ? W2 : g == 3 ? W3 : W4;
            Wt[id] = f2b(W[k * 128 + j]);
        }
    } else {
        int e = (b - 320) * 256 + t;
        if (e < E) atomicAdd(&cnt[dst[e]], 1);
    }
}

// ---------------- fused 5-GEMM: out_g = X @ W_g, A-tile staged ONCE ----------------
__global__ __launch_bounds__(256) void k_gemm(const float* __restrict__ X, const u16* __restrict__ Wt,
                                              u16* __restrict__ H, u16* __restrict__ Q, u16* __restrict__ K,
                                              u16* __restrict__ V, u16* __restrict__ R,
                                              const float* __restrict__ asrc, const float* __restrict__ adst,
                                              float* __restrict__ a_s, float* __restrict__ a_d, int N) {
    __shared__ u16 As[64][136];
    __shared__ u16 Bs[128][136];
    const int tid = threadIdx.x;
    const int row0 = blockIdx.x * 64;

    for (int c = tid; c < 64 * 16; c += 256) {
        int r = c >> 4, col8 = (c & 15) * 8;
        int grow = row0 + r;
        short8 vv = {0, 0, 0, 0, 0, 0, 0, 0};
        if (grow < N) {
            const float* xp = X + (size_t)grow * 128 + col8;
            float4 f0 = *reinterpret_cast<const float4*>(xp);
            float4 f1 = *reinterpret_cast<const float4*>(xp + 4);
            vv[0] = (short)f2b(f0.x); vv[1] = (short)f2b(f0.y);
            vv[2] = (short)f2b(f0.z); vv[3] = (short)f2b(f0.w);
            vv[4] = (short)f2b(f1.x); vv[5] = (short)f2b(f1.y);
            vv[6] = (short)f2b(f1.z); vv[7] = (short)f2b(f1.w);
        }
        *reinterpret_cast<short8*>(&As[r][col8]) = vv;
    }
    for (int c = tid; c < 128 * 16; c += 256) {
        int r = c >> 4, col8 = (c & 15) * 8;
        *reinterpret_cast<short8*>(&Bs[r][col8]) =
            *reinterpret_cast<const short8*>(Wt + r * 128 + col8);
    }
    __syncthreads();

    const int wid = tid >> 6, lane = tid & 63;
    const int l15 = lane & 15;
    const int arow = wid * 16 + l15;
    const int kg = (lane >> 4) * 8;

    short8 af[4];
#pragma unroll
    for (int kc = 0; kc < 4; kc++)
        af[kc] = *reinterpret_cast<const short8*>(&As[arow][kc * 32 + kg]);

    const int rbase = row0 + wid * 16 + ((lane >> 4) << 2);

    for (int g = 0; g < 5; g++) {
        u16* outp = g == 0 ? H : g == 1 ? Q : g == 2 ? K : g == 3 ? V : R;
        float ps[4] = {0.f, 0.f, 0.f, 0.f};
        float pd[4] = {0.f, 0.f, 0.f, 0.f};

#pragma unroll
        for (int c = 0; c < 8; c++) {
            const int bcol = c * 16 + l15;
            f32x4 acc = {0.f, 0.f, 0.f, 0.f};
#pragma unroll
            for (int kc = 0; kc < 4; kc++) {
                short8 bf = *reinterpret_cast<const short8*>(&Bs[bcol][kc * 32 + kg]);
                acc = __builtin_amdgcn_mfma_f32_16x16x32_bf16(af[kc], bf, acc, 0, 0, 0);
            }
#pragma unroll
            for (int r = 0; r < 4; r++) {
                int grow = rbase + r;
                if (grow < N) outp[(size_t)grow * 128 + bcol] = f2b(acc[r]);
            }
            if (g == 0) {
                float vs = asrc[bcol], vd = adst[bcol];
#pragma unroll
                for (int r = 0; r < 4; r++) {
                    ps[r] += acc[r] * vs;
                    pd[r] += acc[r] * vd;
                }
            }
        }
        if (g == 0) {
#pragma unroll
            for (int off = 1; off < 16; off <<= 1) {
#pragma unroll
                for (int r = 0; r < 4; r++) {
                    ps[r] += __shfl_xor(ps[r], off);
                    pd[r] += __shfl_xor(pd[r], off);
                }
            }
            if (l15 == 0) {
#pragma unroll
                for (int r = 0; r < 4; r++) {
                    int grow = rbase + r;
                    if (grow < N) { a_s[grow] = ps[r]; a_d[grow] = pd[r]; }
                }
            }
        }
        if (g < 4) {
            __syncthreads();
            const u16* wt = Wt + (g + 1) * 16384;
            for (int c = tid; c < 128 * 16; c += 256) {
                int r = c >> 4, col8 = (c & 15) * 8;
                *reinterpret_cast<short8*>(&Bs[r][col8]) =
                    *reinterpret_cast<const short8*>(wt + r * 128 + col8);
            }
            __syncthreads();
        }
    }
}

// ---------------- CSR scan chain ----------------
__global__ __launch_bounds__(256) void k_scan1(const int* __restrict__ cnt, int* __restrict__ excl,
                                               int* __restrict__ bsum, int N) {
    __shared__ int sh[256];
    int t = threadIdx.x;
    int base = blockIdx.x * 1024 + t * 4;
    int v[4], s = 0;
#pragma unroll
    for (int j = 0; j < 4; j++) {
        int i = base + j;
        v[j] = (i < N) ? cnt[i] : 0;
        s += v[j];
    }
    sh[t] = s;
    __syncthreads();
    for (int off = 1; off < 256; off <<= 1) {
        int x = (t >= off) ? sh[t - off] : 0;
        __syncthreads();
        sh[t] += x;
        __syncthreads();
    }
    int run = sh[t] - s;
#pragma unroll
    for (int j = 0; j < 4; j++) {
        int i = base + j;
        if (i < N) excl[i] = run;
        run += v[j];
    }
    if (t == 255) bsum[blockIdx.x] = sh[255];
}

__global__ __launch_bounds__(256) void k_scan2(const int* __restrict__ bsum, int* __restrict__ boff,
                                               int nb, int* __restrict__ rp_last) {
    __shared__ int sh[256];
    int t = threadIdx.x;
    int v = (t < nb) ? bsum[t] : 0;
    sh[t] = v;
    __syncthreads();
    for (int off = 1; off < 256; off <<= 1) {
        int x = (t >= off) ? sh[t - off] : 0;
        __syncthreads();
        sh[t] += x;
        __syncthreads();
    }
    if (t < nb) boff[t] = sh[t] - v;
    if (t == 255) *rp_last = sh[255];
}

__global__ void k_scan3(int* __restrict__ rp, const int* __restrict__ boff, int* __restrict__ next, int N) {
    int i = blockIdx.x * 256 + threadIdx.x;
    if (i < N) {
        int v = rp[i] + boff[i >> 10];
        rp[i] = v;
        next[i] = v;
    }
}

__global__ void k_fill(const int* __restrict__ src, const int* __restrict__ dst, int* __restrict__ next,
                       int* __restrict__ csrc, int E) {
    int e = blockIdx.x * 256 + threadIdx.x;
    if (e < E) {
        int p = atomicAdd(&next[dst[e]], 1);
        csrc[p] = src[e];
    }
}

// ---------------- phase A: per-edge softmax weights (both branches) ----------------
// Wave per node; 4 edges concurrently via 16-lane groups; lane holds 8 dims (dwordx4).
// No max-subtraction (logits bounded; softmax shift-invariant; validated r1/r2).
__global__ __launch_bounds__(256) void k_tlog(const int* __restrict__ rp, const int* __restrict__ csrc,
                                              const u16* __restrict__ Q, const u16* __restrict__ K,
                                              const float* __restrict__ a_s, const float* __restrict__ a_d,
                                              float2* __restrict__ w2, int N) {
    const int wid = threadIdx.x >> 6, lane = threadIdx.x & 63;
    const int n = blockIdx.x * 4 + wid;
    if (n >= N) return;
    const int l = lane & 15, g = lane >> 4;

    u32x4 qv = *reinterpret_cast<const u32x4*>(Q + (size_t)n * 128 + l * 8);
    float qf[8];
#pragma unroll
    for (int i = 0; i < 4; i++) { qf[2 * i] = blo(qv[i]); qf[2 * i + 1] = bhi(qv[i]); }
    const float adn = a_d[n];
    const int beg = rp[n], end = rp[n + 1];
    const float isd = 0.08838834764831845f;   // 1/sqrt(128)

    for (int p = beg; p < end; p += 4) {
        int pe = p + g;                       // group-uniform
        if (pe < end) {
            int s = csrc[pe];
            u32x4 kv = *reinterpret_cast<const u32x4*>(K + (size_t)s * 128 + l * 8);
            float dt = 0.f;
#pragma unroll
            for (int i = 0; i < 4; i++) {
                dt = fmaf(qf[2 * i], blo(kv[i]), dt);
                dt = fmaf(qf[2 * i + 1], bhi(kv[i]), dt);
            }
#pragma unroll
            for (int off = 1; off < 16; off <<= 1) dt += __shfl_xor(dt, off);
            if (l == 0) {
                float gl = a_s[s] + adn;
                gl = gl >= 0.f ? gl : 0.2f * gl;          // LeakyReLU(0.2)
                float2 w;
                w.x = __expf(gl);
                w.y = __expf(dt * isd);
                w2[pe] = w;
            }
        }
    }
}

// ---------------- phase B: streaming weighted aggregation + fused epilogue ----------------
__global__ __launch_bounds__(256) void k_agg2(const int* __restrict__ rp, const int* __restrict__ csrc,
                                              const u16* __restrict__ H, const u16* __restrict__ V,
                                              const u16* __restrict__ R, const float2* __restrict__ w2,
                                              const float* __restrict__ bias, float* __restrict__ out, int N) {
    const int wid = threadIdx.x >> 6, lane = threadIdx.x & 63;
    const int n = blockIdx.x * 4 + wid;
    if (n >= N) return;
    const int l = lane & 15, g = lane >> 4;

    float ag[8] = {0.f, 0.f, 0.f, 0.f, 0.f, 0.f, 0.f, 0.f};
    float at[8] = {0.f, 0.f, 0.f, 0.f, 0.f, 0.f, 0.f, 0.f};
    float zg = 0.f, zt = 0.f;
    const int beg = rp[n], end = rp[n + 1];

    for (int p = beg; p < end; p += 4) {
        int pe = p + g;
        if (pe < end) {
            int s = csrc[pe];
            float2 w = w2[pe];
            u32x4 hv = *reinterpret_cast<const u32x4*>(H + (size_t)s * 128 + l * 8);
            u32x4 vv = *reinterpret_cast<const u32x4*>(V + (size_t)s * 128 + l * 8);
#pragma unroll
            for (int i = 0; i < 4; i++) {
                ag[2 * i]     = fmaf(w.x, blo(hv[i]), ag[2 * i]);
                ag[2 * i + 1] = fmaf(w.x, bhi(hv[i]), ag[2 * i + 1]);
                at[2 * i]     = fmaf(w.y, blo(vv[i]), at[2 * i]);
                at[2 * i + 1] = fmaf(w.y, bhi(vv[i]), at[2 * i + 1]);
            }
            zg += w.x;
            zt += w.y;
        }
    }

    // cross-group reduce (groups processed disjoint edge subsets)
#pragma unroll
    for (int j = 0; j < 8; j++) {
        ag[j] += __shfl_xor(ag[j], 16); ag[j] += __shfl_xor(ag[j], 32);
        at[j] += __shfl_xor(at[j], 16); at[j] += __shfl_xor(at[j], 32);
    }
    zg += __shfl_xor(zg, 16); zg += __shfl_xor(zg, 32);
    zt += __shfl_xor(zt, 16); zt += __shfl_xor(zt, 32);

    float ig = 1.f / (zg + 1e-16f), it = 1.f / (zt + 1e-16f);
    u32x4 rv = *reinterpret_cast<const u32x4*>(R + (size_t)n * 128 + l * 8);
    float4 b0 = *reinterpret_cast<const float4*>(bias + l * 8);
    float4 b1 = *reinterpret_cast<const float4*>(bias + l * 8 + 4);
    float bb[8] = {b0.x, b0.y, b0.z, b0.w, b1.x, b1.y, b1.z, b1.w};

    float o[8];
    float ss = 0.f;
#pragma unroll
    for (int i = 0; i < 4; i++) {
        float r0 = blo(rv[i]), r1 = bhi(rv[i]);
        float g0 = fmaxf(ag[2 * i] * ig + bb[2 * i], 0.f);
        float g1 = fmaxf(ag[2 * i + 1] * ig + bb[2 * i + 1], 0.f);
        o[2 * i] = g0 + at[2 * i] * it + r0;
        o[2 * i + 1] = g1 + at[2 * i + 1] * it + r1;
        ss += o[2 * i] * o[2 * i] + o[2 * i + 1] * o[2 * i + 1];
    }
#pragma unroll
    for (int off = 1; off < 16; off <<= 1) ss += __shfl_xor(ss, off);
    float inv = 1.f / fmaxf(sqrtf(ss), 1e-12f);

    if (g == 0) {
        float4 s0 = {o[0] * inv, o[1] * inv, o[2] * inv, o[3] * inv};
        float4 s1 = {o[4] * inv, o[5] * inv, o[6] * inv, o[7] * inv};
        float* op = out + (size_t)n * 128 + l * 8;
        *reinterpret_cast<float4*>(op) = s0;
        *reinterpret_cast<float4*>(op + 4) = s1;
    }
}

// ---------------- host launcher ----------------
extern "C" void kernel_launch(void* const* d_in, const int* in_sizes, int n_in,
                              void* d_out, int out_size, void* d_ws, size_t ws_size,
                              hipStream_t stream) {
    const int* edge = (const int*)d_in[1];
    const float* emb = (const float*)d_in[2];
    const float* gat_W = (const float*)d_in[3];
    const float* a_src = (const float*)d_in[4];
    const float* a_dst = (const float*)d_in[5];
    const float* bias = (const float*)d_in[6];
    const float* Wq = (const float*)d_in[7];
    const float* Wk = (const float*)d_in[8];
    const float* Wv = (const float*)d_in[9];
    const float* Wr = (const float*)d_in[10];

    const int E = in_sizes[1] / 2;
    const int N = in_sizes[2] / 128;
    const int* src = edge;
    const int* dst = edge + E;
    float* out = (float*)d_out;

    char* w = (char*)d_ws;
    auto alloc = [&](size_t bytes) -> char* {
        char* p = w;
        w += (bytes + 255) & ~(size_t)255;
        return p;
    };
    u16* H = (u16*)alloc((size_t)N * 128 * 2);
    u16* Q = (u16*)alloc((size_t)N * 128 * 2);
    u16* K = (u16*)alloc((size_t)N * 128 * 2);
    u16* V = (u16*)alloc((size_t)N * 128 * 2);
    u16* R = (u16*)alloc((size_t)N * 128 * 2);
    u16* Wt = (u16*)alloc(5 * 128 * 128 * 2);
    float* a_s = (float*)alloc((size_t)N * 4);
    float* a_d = (float*)alloc((size_t)N * 4);
    int* cnt = (int*)alloc((size_t)N * 4);
    int* rp = (int*)alloc((size_t)(N + 1) * 4);
    int* nxt = (int*)alloc((size_t)N * 4);
    int* bsum = (int*)alloc(1024);
    int* boff = (int*)alloc(1024);
    int* csrc = (int*)alloc((size_t)E * 4);
    float2* w2 = (float2*)alloc((size_t)E * 8);

    const int nb = (N + 1023) / 1024;
    const int nhist = (E + 255) / 256;

    hipMemsetAsync(cnt, 0, (size_t)N * 4, stream);
    k_ph<<<320 + nhist, 256, 0, stream>>>(gat_W, Wq, Wk, Wv, Wr, Wt, dst, cnt, E);
    k_gemm<<<(N + 63) / 64, 256, 0, stream>>>(emb, Wt, H, Q, K, V, R, a_src, a_dst, a_s, a_d, N);
    k_scan1<<<nb, 256, 0, stream>>>(cnt, rp, bsum, N);
    k_scan2<<<1, 256, 0, stream>>>(bsum, boff, nb, rp + N);
    k_scan3<<<(N + 255) / 256, 256, 0, stream>>>(rp, boff, nxt, N);
    k_fill<<<nhist, 256, 0, stream>>>(src, dst, nxt, csrc, E);
    k_tlog<<<(N + 3) / 4, 256, 0, stream>>>(rp, csrc, Q, K, a_s, a_d, w2, N);
    k_agg2<<<(N + 3) / 4, 256, 0, stream>>>(rp, csrc, H, V, R, w2, bias, out, N);
}

// Round 4
// 204.583 us; speedup vs baseline: 1.1758x; 1.1758x over previous
//
#include <hip/hip_runtime.h>

typedef unsigned short u16;
typedef unsigned int   u32;
typedef __attribute__((ext_vector_type(8))) short short8;
typedef __attribute__((ext_vector_type(4))) unsigned int u32x4;
typedef __attribute__((ext_vector_type(4))) float f32x4;

__device__ __forceinline__ u16 f2b(float f) {
    u32 u = __float_as_uint(f);
    u32 r = (u + 0x7fffu + ((u >> 16) & 1u)) >> 16;   // round-to-nearest-even
    return (u16)r;
}
__device__ __forceinline__ float blo(u32 w) { return __uint_as_float(w << 16); }
__device__ __forceinline__ float bhi(u32 w) { return __uint_as_float(w & 0xffff0000u); }

// ---------------- prep weights (transpose+bf16) AND edge histogram, one launch ----------------
__global__ void k_ph(const float* __restrict__ W0, const float* __restrict__ W1,
                     const float* __restrict__ W2, const float* __restrict__ W3,
                     const float* __restrict__ W4, u16* __restrict__ Wt,
                     const int* __restrict__ dst, int* __restrict__ cnt, int E) {
    int b = blockIdx.x, t = threadIdx.x;
    if (b < 320) {
        int id = b * 256 + t;
        if (id < 5 * 16384) {
            int g = id >> 14, j = (id >> 7) & 127, k = id & 127;
            const float* W = g == 0 ? W0 : g == 1 ? W1 : g == 2 ? W2 : g == 3 ? W3 : W4;
            Wt[id] = f2b(W[k * 128 + j]);
        }
    } else {
        int e = (b - 320) * 256 + t;
        if (e < E) atomicAdd(&cnt[dst[e]], 1);
    }
}

// ---------------- fused 5-GEMM, single 34.8KB LDS buffer (A then B tiles) ----------------
// H/K/V interleaved into HKV[n][3][128] (H:+0, K:+128, V:+256); Q,R separate.
// Also computes a_s/a_d in the g==0 epilogue.
__global__ __launch_bounds__(256) void k_gemm(const float* __restrict__ X, const u16* __restrict__ Wt,
                                              u16* __restrict__ HKV, u16* __restrict__ Q, u16* __restrict__ R,
                                              const float* __restrict__ asrc, const float* __restrict__ adst,
                                              float* __restrict__ a_s, float* __restrict__ a_d, int N) {
    __shared__ u16 smem[128][136];   // 34.8 KB: rows 0-63 = A tile, then reused for B tiles
    const int tid = threadIdx.x;
    const int row0 = blockIdx.x * 64;

    // stage A (fp32 -> bf16) into rows 0..63
    for (int c = tid; c < 64 * 16; c += 256) {
        int r = c >> 4, col8 = (c & 15) * 8;
        int grow = row0 + r;
        short8 vv = {0, 0, 0, 0, 0, 0, 0, 0};
        if (grow < N) {
            const float* xp = X + (size_t)grow * 128 + col8;
            float4 f0 = *reinterpret_cast<const float4*>(xp);
            float4 f1 = *reinterpret_cast<const float4*>(xp + 4);
            vv[0] = (short)f2b(f0.x); vv[1] = (short)f2b(f0.y);
            vv[2] = (short)f2b(f0.z); vv[3] = (short)f2b(f0.w);
            vv[4] = (short)f2b(f1.x); vv[5] = (short)f2b(f1.y);
            vv[6] = (short)f2b(f1.z); vv[7] = (short)f2b(f1.w);
        }
        *reinterpret_cast<short8*>(&smem[r][col8]) = vv;
    }
    __syncthreads();

    const int wid = tid >> 6, lane = tid & 63;
    const int l15 = lane & 15;
    const int arow = wid * 16 + l15;
    const int kg = (lane >> 4) * 8;

    short8 af[4];
#pragma unroll
    for (int kc = 0; kc < 4; kc++)
        af[kc] = *reinterpret_cast<const short8*>(&smem[arow][kc * 32 + kg]);
    __syncthreads();   // A no longer needed; buffer becomes B tile

    const int rbase = row0 + wid * 16 + ((lane >> 4) << 2);

    for (int g = 0; g < 5; g++) {
        // stage B_g
        const u16* wt = Wt + g * 16384;
        for (int c = tid; c < 128 * 16; c += 256) {
            int r = c >> 4, col8 = (c & 15) * 8;
            *reinterpret_cast<short8*>(&smem[r][col8]) =
                *reinterpret_cast<const short8*>(wt + r * 128 + col8);
        }
        __syncthreads();

        // output pointer + row stride (H/K/V interleaved)
        u16* outp;
        int stride;
        if (g == 0)      { outp = HKV;       stride = 384; }
        else if (g == 1) { outp = Q;         stride = 128; }
        else if (g == 2) { outp = HKV + 128; stride = 384; }
        else if (g == 3) { outp = HKV + 256; stride = 384; }
        else             { outp = R;         stride = 128; }

        float ps[4] = {0.f, 0.f, 0.f, 0.f};
        float pd[4] = {0.f, 0.f, 0.f, 0.f};

#pragma unroll
        for (int c = 0; c < 8; c++) {
            const int bcol = c * 16 + l15;
            f32x4 acc = {0.f, 0.f, 0.f, 0.f};
#pragma unroll
            for (int kc = 0; kc < 4; kc++) {
                short8 bf = *reinterpret_cast<const short8*>(&smem[bcol][kc * 32 + kg]);
                acc = __builtin_amdgcn_mfma_f32_16x16x32_bf16(af[kc], bf, acc, 0, 0, 0);
            }
#pragma unroll
            for (int r = 0; r < 4; r++) {
                int grow = rbase + r;
                if (grow < N) outp[(size_t)grow * stride + bcol] = f2b(acc[r]);
            }
            if (g == 0) {
                float vs = asrc[bcol], vd = adst[bcol];
#pragma unroll
                for (int r = 0; r < 4; r++) {
                    ps[r] += acc[r] * vs;
                    pd[r] += acc[r] * vd;
                }
            }
        }
        if (g == 0) {
#pragma unroll
            for (int off = 1; off < 16; off <<= 1) {
#pragma unroll
                for (int r = 0; r < 4; r++) {
                    ps[r] += __shfl_xor(ps[r], off);
                    pd[r] += __shfl_xor(pd[r], off);
                }
            }
            if (l15 == 0) {
#pragma unroll
                for (int r = 0; r < 4; r++) {
                    int grow = rbase + r;
                    if (grow < N) { a_s[grow] = ps[r]; a_d[grow] = pd[r]; }
                }
            }
        }
        __syncthreads();   // compute done before next B overwrite
    }
}

// ---------------- CSR scan chain ----------------
__global__ __launch_bounds__(256) void k_scan1(const int* __restrict__ cnt, int* __restrict__ excl,
                                               int* __restrict__ bsum, int N) {
    __shared__ int sh[256];
    int t = threadIdx.x;
    int base = blockIdx.x * 1024 + t * 4;
    int v[4], s = 0;
#pragma unroll
    for (int j = 0; j < 4; j++) {
        int i = base + j;
        v[j] = (i < N) ? cnt[i] : 0;
        s += v[j];
    }
    sh[t] = s;
    __syncthreads();
    for (int off = 1; off < 256; off <<= 1) {
        int x = (t >= off) ? sh[t - off] : 0;
        __syncthreads();
        sh[t] += x;
        __syncthreads();
    }
    int run = sh[t] - s;
#pragma unroll
    for (int j = 0; j < 4; j++) {
        int i = base + j;
        if (i < N) excl[i] = run;
        run += v[j];
    }
    if (t == 255) bsum[blockIdx.x] = sh[255];
}

__global__ __launch_bounds__(256) void k_scan2(const int* __restrict__ bsum, int* __restrict__ boff,
                                               int nb, int* __restrict__ rp_last) {
    __shared__ int sh[256];
    int t = threadIdx.x;
    int v = (t < nb) ? bsum[t] : 0;
    sh[t] = v;
    __syncthreads();
    for (int off = 1; off < 256; off <<= 1) {
        int x = (t >= off) ? sh[t - off] : 0;
        __syncthreads();
        sh[t] += x;
        __syncthreads();
    }
    if (t < nb) boff[t] = sh[t] - v;
    if (t == 255) *rp_last = sh[255];
}

__global__ void k_scan3(int* __restrict__ rp, const int* __restrict__ boff, int* __restrict__ next, int N) {
    int i = blockIdx.x * 256 + threadIdx.x;
    if (i < N) {
        int v = rp[i] + boff[i >> 10];
        rp[i] = v;
        next[i] = v;
    }
}

__global__ void k_fill(const int* __restrict__ src, const int* __restrict__ dst, int* __restrict__ next,
                       int* __restrict__ csrc, int E) {
    int e = blockIdx.x * 256 + threadIdx.x;
    if (e < E) {
        int p = atomicAdd(&next[dst[e]], 1);
        csrc[p] = src[e];
    }
}

// ---------------- fused edge phase: weights inline + aggregation + epilogue ----------------
// Wave per node; 4 edges concurrently via 16-lane groups; lane holds 8 dims (dwordx4).
// No max-subtraction (logits bounded; softmax shift-invariant; validated r1-r3).
__global__ __launch_bounds__(256) void k_edge(const int* __restrict__ rp, const int* __restrict__ csrc,
                                              const u16* __restrict__ HKV, const u16* __restrict__ Q,
                                              const u16* __restrict__ R, const float* __restrict__ a_s,
                                              const float* __restrict__ a_d, const float* __restrict__ bias,
                                              float* __restrict__ out, int N) {
    const int wid = threadIdx.x >> 6, lane = threadIdx.x & 63;
    const int n = blockIdx.x * 4 + wid;
    if (n >= N) return;
    const int l = lane & 15, g = lane >> 4;

    u32x4 qv = *reinterpret_cast<const u32x4*>(Q + (size_t)n * 128 + l * 8);
    float qf[8];
#pragma unroll
    for (int i = 0; i < 4; i++) { qf[2 * i] = blo(qv[i]); qf[2 * i + 1] = bhi(qv[i]); }
    const float adn = a_d[n];
    const int beg = rp[n], end = rp[n + 1];
    const float isd = 0.08838834764831845f;   // 1/sqrt(128)

    float ag[8] = {0.f, 0.f, 0.f, 0.f, 0.f, 0.f, 0.f, 0.f};
    float at[8] = {0.f, 0.f, 0.f, 0.f, 0.f, 0.f, 0.f, 0.f};
    float zg = 0.f, zt = 0.f;

    for (int p = beg; p < end; p += 4) {
        int pe = p + g;                       // group-uniform
        if (pe < end) {
            int s = csrc[pe];
            const u16* base = HKV + (size_t)s * 384;
            u32x4 kv = *reinterpret_cast<const u32x4*>(base + 128 + l * 8);
            u32x4 hv = *reinterpret_cast<const u32x4*>(base + l * 8);
            u32x4 vv = *reinterpret_cast<const u32x4*>(base + 256 + l * 8);
            float as0 = a_s[s];

            float dt = 0.f;
#pragma unroll
            for (int i = 0; i < 4; i++) {
                dt = fmaf(qf[2 * i], blo(kv[i]), dt);
                dt = fmaf(qf[2 * i + 1], bhi(kv[i]), dt);
            }
#pragma unroll
            for (int off = 1; off < 16; off <<= 1) dt += __shfl_xor(dt, off);

            float gl = as0 + adn;
            gl = gl >= 0.f ? gl : 0.2f * gl;  // LeakyReLU(0.2)
            float wg = __expf(gl);
            float wt = __expf(dt * isd);

#pragma unroll
            for (int i = 0; i < 4; i++) {
                ag[2 * i]     = fmaf(wg, blo(hv[i]), ag[2 * i]);
                ag[2 * i + 1] = fmaf(wg, bhi(hv[i]), ag[2 * i + 1]);
                at[2 * i]     = fmaf(wt, blo(vv[i]), at[2 * i]);
                at[2 * i + 1] = fmaf(wt, bhi(vv[i]), at[2 * i + 1]);
            }
            zg += wg;
            zt += wt;
        }
    }

    // cross-group reduce (groups processed disjoint edge subsets)
#pragma unroll
    for (int j = 0; j < 8; j++) {
        ag[j] += __shfl_xor(ag[j], 16); ag[j] += __shfl_xor(ag[j], 32);
        at[j] += __shfl_xor(at[j], 16); at[j] += __shfl_xor(at[j], 32);
    }
    zg += __shfl_xor(zg, 16); zg += __shfl_xor(zg, 32);
    zt += __shfl_xor(zt, 16); zt += __shfl_xor(zt, 32);

    float ig = 1.f / (zg + 1e-16f), it = 1.f / (zt + 1e-16f);
    u32x4 rv = *reinterpret_cast<const u32x4*>(R + (size_t)n * 128 + l * 8);
    float4 b0 = *reinterpret_cast<const float4*>(bias + l * 8);
    float4 b1 = *reinterpret_cast<const float4*>(bias + l * 8 + 4);
    float bb[8] = {b0.x, b0.y, b0.z, b0.w, b1.x, b1.y, b1.z, b1.w};

    float o[8];
    float ss = 0.f;
#pragma unroll
    for (int i = 0; i < 4; i++) {
        float r0 = blo(rv[i]), r1 = bhi(rv[i]);
        float g0 = fmaxf(ag[2 * i] * ig + bb[2 * i], 0.f);
        float g1 = fmaxf(ag[2 * i + 1] * ig + bb[2 * i + 1], 0.f);
        o[2 * i] = g0 + at[2 * i] * it + r0;
        o[2 * i + 1] = g1 + at[2 * i + 1] * it + r1;
        ss += o[2 * i] * o[2 * i] + o[2 * i + 1] * o[2 * i + 1];
    }
#pragma unroll
    for (int off = 1; off < 16; off <<= 1) ss += __shfl_xor(ss, off);
    float inv = 1.f / fmaxf(sqrtf(ss), 1e-12f);

    if (g == 0) {
        float4 s0 = {o[0] * inv, o[1] * inv, o[2] * inv, o[3] * inv};
        float4 s1 = {o[4] * inv, o[5] * inv, o[6] * inv, o[7] * inv};
        float* op = out + (size_t)n * 128 + l * 8;
        *reinterpret_cast<float4*>(op) = s0;
        *reinterpret_cast<float4*>(op + 4) = s1;
    }
}

// ---------------- host launcher ----------------
extern "C" void kernel_launch(void* const* d_in, const int* in_sizes, int n_in,
                              void* d_out, int out_size, void* d_ws, size_t ws_size,
                              hipStream_t stream) {
    const int* edge = (const int*)d_in[1];
    const float* emb = (const float*)d_in[2];
    const float* gat_W = (const float*)d_in[3];
    const float* a_src = (const float*)d_in[4];
    const float* a_dst = (const float*)d_in[5];
    const float* bias = (const float*)d_in[6];
    const float* Wq = (const float*)d_in[7];
    const float* Wk = (const float*)d_in[8];
    const float* Wv = (const float*)d_in[9];
    const float* Wr = (const float*)d_in[10];

    const int E = in_sizes[1] / 2;
    const int N = in_sizes[2] / 128;
    const int* src = edge;
    const int* dst = edge + E;
    float* out = (float*)d_out;

    char* w = (char*)d_ws;
    auto alloc = [&](size_t bytes) -> char* {
        char* p = w;
        w += (bytes + 255) & ~(size_t)255;
        return p;
    };
    u16* HKV = (u16*)alloc((size_t)N * 384 * 2);    // [n][H|K|V][128]
    u16* Q   = (u16*)alloc((size_t)N * 128 * 2);
    u16* R   = (u16*)alloc((size_t)N * 128 * 2);
    u16* Wt  = (u16*)alloc(5 * 128 * 128 * 2);
    float* a_s = (float*)alloc((size_t)N * 4);
    float* a_d = (float*)alloc((size_t)N * 4);
    int* cnt  = (int*)alloc((size_t)N * 4);
    int* rp   = (int*)alloc((size_t)(N + 1) * 4);
    int* nxt  = (int*)alloc((size_t)N * 4);
    int* bsum = (int*)alloc(1024);
    int* boff = (int*)alloc(1024);
    int* csrc = (int*)alloc((size_t)E * 4);

    const int nb = (N + 1023) / 1024;
    const int nhist = (E + 255) / 256;

    hipMemsetAsync(cnt, 0, (size_t)N * 4, stream);
    k_ph<<<320 + nhist, 256, 0, stream>>>(gat_W, Wq, Wk, Wv, Wr, Wt, dst, cnt, E);
    k_gemm<<<(N + 63) / 64, 256, 0, stream>>>(emb, Wt, HKV, Q, R, a_src, a_dst, a_s, a_d, N);
    k_scan1<<<nb, 256, 0, stream>>>(cnt, rp, bsum, N);
    k_scan2<<<1, 256, 0, stream>>>(bsum, boff, nb, rp + N);
    k_scan3<<<(N + 255) / 256, 256, 0, stream>>>(rp, boff, nxt, N);
    k_fill<<<nhist, 256, 0, stream>>>(src, dst, nxt, csrc, E);
    k_edge<<<(N + 3) / 4, 256, 0, stream>>>(rp, csrc, HKV, Q, R, a_s, a_d, bias, out, N);
}